// Round 10
// baseline (609.198 us; speedup 1.0000x reference)
//
#include <hip/hip_runtime.h>

#define N_WALK 4096
#define N_EL   32
#define DIM    64
#define HPAD   68   // f32 row stride: 68%32=4 banks -> max 2-way conflict (free)
#define NLAY   3
#define KDET   16
#define NPAIR  496
#define TWO_PI_D 6.283185307179586476925286766559

using f64x4 = __attribute__((ext_vector_type(4))) double;

#define MFMA64(A, B, C) __builtin_amdgcn_mfma_f64_16x16x4f64((A), (B), (C), 0, 0, 0)

// fast f64 exp, rel err ~3e-13 for |x| <= 60
__device__ __forceinline__ double exp_d(double x) {
  const double LOG2E  = 1.4426950408889634074;
  const double LN2_HI = 6.93147180369123816490e-01;
  const double LN2_LO = 1.90821492927058770002e-10;
  const double nf = rint(x * LOG2E);
  double r = fma(-nf, LN2_HI, x);
  r = fma(-nf, LN2_LO, r);
  double p = 1.0/3628800.0;
  p = fma(p, r, 1.0/362880.0);
  p = fma(p, r, 1.0/40320.0);
  p = fma(p, r, 1.0/5040.0);
  p = fma(p, r, 1.0/720.0);
  p = fma(p, r, 1.0/120.0);
  p = fma(p, r, 1.0/24.0);
  p = fma(p, r, 1.0/6.0);
  p = fma(p, r, 0.5);
  p = fma(p, r, 1.0);
  p = fma(p, r, 1.0);
  const long long bits = ((long long)((int)nf + 1023)) << 52;
  return p * __longlong_as_double(bits);
}

// silu with Newton-recip division (rel err ~1e-14)
__device__ __forceinline__ double silu_d(double x) {
  const double d = 1.0 + exp_d(-x);
  const double q0 = (double)(1.0f / (float)d);
  double q = q0 * (2.0 - d * q0);
  q = q * (2.0 - d * q);
  return x * q;
}
__device__ __forceinline__ float silu_q(float x) { return x / (1.0f + __expf(-x)); }

__global__ __launch_bounds__(256) void wf_kernel(
    const float* __restrict__ r_el,
    const float* __restrict__ cell,
    const float* __restrict__ W_e,  const float* __restrict__ b_e,
    const float* __restrict__ W_pw, const float* __restrict__ b_pw,
    const float* __restrict__ W1,   const float* __restrict__ b1,
    const float* __restrict__ W2,   const float* __restrict__ b2,
    const float* __restrict__ ln_w, const float* __restrict__ ln_b,
    const float* __restrict__ W_up, const float* __restrict__ b_up,
    const float* __restrict__ W_dn, const float* __restrict__ b_dn,
    const float* __restrict__ det_w,
    const float* __restrict__ Wj1,  const float* __restrict__ bj1,
    const float* __restrict__ Wj2,  const float* __restrict__ bj2,
    const float* __restrict__ Wj3,  const float* __restrict__ bj3,
    const float* __restrict__ jscale,
    float* __restrict__ out)
{
  __shared__ float s_linv[9];
  __shared__ float s_cl[9];
  __shared__ float s_r[N_EL][3];
  __shared__ float s_pw[N_EL][6];
  __shared__ float s_h[N_EL][HPAD];
  // union buffer: stage-3 s_y [32][HPAD]=2176 floats; stage-5 phi [16][257]=4112 floats
  __shared__ float s_u[16*257];
  __shared__ float s_hm[DIM];
  __shared__ double s_hb[DIM];        // b1 + hm @ W1[64:128]  (f64, per layer)
  __shared__ double s_lu[2][KDET];
  __shared__ float  s_su[2][KDET];
  __shared__ float  s_red[4];
#define SY(e,d)   s_u[(e)*HPAD + (d)]
#define SORB(j,c) s_u[(j)*257 + (c)]

  const int t = threadIdx.x;
  const int w = blockIdx.x;
  const int wv = t >> 6;         // wave id 0..3
  const int l  = t & 63;
  const int lr = l & 15;         // row/col fragment index
  const int lq = l >> 4;         // k fragment index

  // ---- cell inverse: f64 compute, f32 round ----
  if (t == 0) {
    double m00=cell[0], m01=cell[1], m02=cell[2];
    double m10=cell[3], m11=cell[4], m12=cell[5];
    double m20=cell[6], m21=cell[7], m22=cell[8];
    double c00 = m11*m22 - m12*m21;
    double c10 = m12*m20 - m10*m22;
    double c20 = m10*m21 - m11*m20;
    double det = m00*c00 + m01*c10 + m02*c20;
    double id = 1.0/det;
    s_linv[0]=(float)(c00*id); s_linv[1]=(float)((m02*m21-m01*m22)*id); s_linv[2]=(float)((m01*m12-m02*m11)*id);
    s_linv[3]=(float)(c10*id); s_linv[4]=(float)((m00*m22-m02*m20)*id); s_linv[5]=(float)((m02*m10-m00*m12)*id);
    s_linv[6]=(float)(c20*id); s_linv[7]=(float)((m01*m20-m00*m21)*id); s_linv[8]=(float)((m00*m11-m01*m10)*id);
    #pragma unroll
    for (int i=0;i<9;i++) s_cl[i]=cell[i];
  }
  __syncthreads();

  // ---- stage 1: wrap + plane waves (f64 dots, f32 tensor boundaries) ----
  if (t < N_EL) {
    const float* rp = r_el + ((size_t)w * N_EL + t) * 3;
    const float rx = rp[0], ry = rp[1], rz = rp[2];
    float s0 = (float)((double)s_linv[0]*rx + (double)s_linv[1]*ry + (double)s_linv[2]*rz);
    float s1 = (float)((double)s_linv[3]*rx + (double)s_linv[4]*ry + (double)s_linv[5]*rz);
    float s2 = (float)((double)s_linv[6]*rx + (double)s_linv[7]*ry + (double)s_linv[8]*rz);
    s0 -= floorf(s0); s1 -= floorf(s1); s2 -= floorf(s2);
    const float wx = (float)((double)s0*s_cl[0] + (double)s1*s_cl[3] + (double)s2*s_cl[6]);
    const float wy = (float)((double)s0*s_cl[1] + (double)s1*s_cl[4] + (double)s2*s_cl[7]);
    const float wz = (float)((double)s0*s_cl[2] + (double)s1*s_cl[5] + (double)s2*s_cl[8]);
    s_r[t][0]=wx; s_r[t][1]=wy; s_r[t][2]=wz;
    const float u0 = (float)((double)s_linv[0]*wx + (double)s_linv[1]*wy + (double)s_linv[2]*wz);
    const float u1 = (float)((double)s_linv[3]*wx + (double)s_linv[4]*wy + (double)s_linv[5]*wz);
    const float u2 = (float)((double)s_linv[6]*wx + (double)s_linv[7]*wy + (double)s_linv[8]*wz);
    double sn, cs;
    sincos(TWO_PI_D*(double)u0, &sn, &cs); s_pw[t][0]=(float)sn; s_pw[t][3]=(float)cs;
    sincos(TWO_PI_D*(double)u1, &sn, &cs); s_pw[t][1]=(float)sn; s_pw[t][4]=(float)cs;
    sincos(TWO_PI_D*(double)u2, &sn, &cs); s_pw[t][2]=(float)sn; s_pw[t][5]=(float)cs;
  }
  __syncthreads();

  // ---- stage 2: h0 (f64 acc -> f32 store) ----
  {
    const int e = t >> 3, db = (t & 7) * 8;
    const double rx=s_r[e][0], ry=s_r[e][1], rz=s_r[e][2];
    const double p0=s_pw[e][0],p1=s_pw[e][1],p2=s_pw[e][2];
    const double p3=s_pw[e][3],p4=s_pw[e][4],p5=s_pw[e][5];
    #pragma unroll
    for (int u=0;u<8;u++) {
      const int d = db+u;
      double acc = (double)b_e[d] + (double)b_pw[d];
      acc = fma(rx, (double)W_e[0*DIM+d], acc);
      acc = fma(ry, (double)W_e[1*DIM+d], acc);
      acc = fma(rz, (double)W_e[2*DIM+d], acc);
      acc = fma(p0, (double)W_pw[0*DIM+d], acc);
      acc = fma(p1, (double)W_pw[1*DIM+d], acc);
      acc = fma(p2, (double)W_pw[2*DIM+d], acc);
      acc = fma(p3, (double)W_pw[3*DIM+d], acc);
      acc = fma(p4, (double)W_pw[4*DIM+d], acc);
      acc = fma(p5, (double)W_pw[5*DIM+d], acc);
      s_h[e][d] = (float)acc;
    }
  }
  __syncthreads();

  const int m  = wv & 1;
  const int nb = (wv >> 1) * 2;
  const int ea = m*16 + lr;        // A-fragment row (electron)
  const int c0 = nb*16 + lr;       // D/B column of tile 0 (tile 1 = c0+16)
  const int er = m*16 + lq*4;      // D row base

  // ---- stage 3: interaction layers via f64 MFMA ----
  for (int L = 0; L < NLAY; ++L) {
    const float* __restrict__ w1p = W1 + (size_t)L*192*DIM;
    const float* __restrict__ w2p = W2 + (size_t)L*DIM*DIM;

    // hm + hb computed PER-WAVE (redundant, bit-identical across waves ->
    // benign race on s_hm/s_hb; wave-internal write->read ordered by lgkmcnt).
    // No block barrier. hb serial-km order identical to R9 (bitwise same).
    {
      double s = 0.0;
      #pragma unroll 8
      for (int e=0;e<N_EL;e++) s += (double)s_h[e][l];
      s_hm[l] = (float)(s * (1.0/N_EL));
      const int c = nb*16 + (l & 31);     // this wave's 32 columns (2x redundant)
      double hb = (double)b1[L*DIM + c];
      #pragma unroll 8
      for (int km=0;km<DIM;km++)
        hb = fma((double)s_hm[km], (double)w1p[(64+km)*DIM + c], hb);
      s_hb[c] = hb;
    }

    // --- y = silu(h@W1a + (h*hm)@W1c + hb) ---
    {
      f64x4 a0 = {0.0,0.0,0.0,0.0}, a1 = {0.0,0.0,0.0,0.0};
      __builtin_amdgcn_s_setprio(1);
      #pragma unroll
      for (int kk=0;kk<16;kk++) {              // K seg 0: x = h
        const int km = kk*4 + lq;
        const double af = (double)s_h[ea][km];
        const double q0 = (double)w1p[km*DIM + c0];
        const double q1 = (double)w1p[km*DIM + c0 + 16];
        a0 = MFMA64(af, q0, a0);
        a1 = MFMA64(af, q1, a1);
      }
      #pragma unroll
      for (int kk=0;kk<16;kk++) {              // K seg 2: x = h*hm (f32 product)
        const int km = kk*4 + lq;
        const double af = (double)(s_h[ea][km] * s_hm[km]);
        const double q0 = (double)w1p[(128+km)*DIM + c0];
        const double q1 = (double)w1p[(128+km)*DIM + c0 + 16];
        a0 = MFMA64(af, q0, a0);
        a1 = MFMA64(af, q1, a1);
      }
      __builtin_amdgcn_s_setprio(0);
      #pragma unroll
      for (int v=0;v<4;v++) {
        const float p0 = (float)(a0[v] + s_hb[c0]);        // np pre-act (f64 reorder)
        const float p1 = (float)(a1[v] + s_hb[c0 + 16]);
        SY(er+v, c0)      = (float)silu_d((double)p0);
        SY(er+v, c0 + 16) = (float)silu_d((double)p1);
      }
    }
    __syncthreads();

    // --- delta = y @ W2 + b2 ; v = h + delta written DIRECTLY to s_h ---
    {
      f64x4 a0 = {0.0,0.0,0.0,0.0}, a1 = {0.0,0.0,0.0,0.0};
      __builtin_amdgcn_s_setprio(1);
      #pragma unroll
      for (int kk=0;kk<16;kk++) {
        const int km = kk*4 + lq;
        const double af = (double)SY(ea, km);
        const double q0 = (double)w2p[km*DIM + c0];
        const double q1 = (double)w2p[km*DIM + c0 + 16];
        a0 = MFMA64(af, q0, a0);
        a1 = MFMA64(af, q1, a1);
      }
      __builtin_amdgcn_s_setprio(0);
      #pragma unroll
      for (int v=0;v<4;v++) {
        const float d0 = (float)(a0[v] + (double)b2[L*DIM + c0]);      // np delta
        const float d1 = (float)(a1[v] + (double)b2[L*DIM + c0 + 16]);
        s_h[er+v][c0]      = s_h[er+v][c0]      + d0;                  // np h+delta
        s_h[er+v][c0 + 16] = s_h[er+v][c0 + 16] + d1;
      }
    }
    __syncthreads();

    // --- LayerNorm: stats f64 (Newton rstd), reads v from s_h, writes s_h ---
    {
      const int e = t >> 3, db = (t & 7) * 8;
      float v[8];
      double ps=0.0, pss=0.0;
      #pragma unroll
      for (int u=0;u<8;u++) {
        v[u] = s_h[e][db+u];
        ps += (double)v[u]; pss += (double)v[u]*(double)v[u];
      }
      #pragma unroll
      for (int off=4; off>=1; off>>=1) {
        ps  += __shfl_xor(ps,  off, 8);
        pss += __shfl_xor(pss, off, 8);
      }
      const double mu = ps * (1.0/DIM);
      double var = pss * (1.0/DIM) - mu*mu;
      var = fmax(var, 0.0);
      const double s = var + 1e-5;
      double rstd = (double)rsqrtf((float)s);
      rstd = rstd * (1.5 - 0.5*s*rstd*rstd);
      rstd = rstd * (1.5 - 0.5*s*rstd*rstd);
      #pragma unroll
      for (int u=0;u<8;u++) {
        const int d = db+u;
        s_h[e][d] = (float)(((double)v[u]-mu)*rstd*(double)ln_w[L*DIM+d] + (double)ln_b[L*DIM+d]);
      }
    }
    __syncthreads();
  }

  // ---- stage 4: Jastrow (f32, fast exp — additive path). No trailing
  //      barrier: stage-5's first barrier orders s_red before stage 7. ----
  float jpart = 0.f;
  for (int p = t; p < NPAIR; p += 256) {
    int i = 0, rem = p;
    while (rem >= (N_EL-1) - i) { rem -= (N_EL-1) - i; ++i; }
    const int j = i + 1 + rem;
    const float dx = s_r[i][0]-s_r[j][0];
    const float dy = s_r[i][1]-s_r[j][1];
    const float dz = s_r[i][2]-s_r[j][2];
    float q0 = (float)((double)s_linv[0]*dx + (double)s_linv[1]*dy + (double)s_linv[2]*dz);
    float q1 = (float)((double)s_linv[3]*dx + (double)s_linv[4]*dy + (double)s_linv[5]*dz);
    float q2 = (float)((double)s_linv[6]*dx + (double)s_linv[7]*dy + (double)s_linv[8]*dz);
    q0 -= rintf(q0); q1 -= rintf(q1); q2 -= rintf(q2);
    const float vx = (float)((double)q0*s_cl[0] + (double)q1*s_cl[3] + (double)q2*s_cl[6]);
    const float vy = (float)((double)q0*s_cl[1] + (double)q1*s_cl[4] + (double)q2*s_cl[7]);
    const float vz = (float)((double)q0*s_cl[2] + (double)q1*s_cl[5] + (double)q2*s_cl[8]);
    const float rij = sqrtf(vx*vx + vy*vy + vz*vz);
    float h1[32];
    #pragma unroll
    for (int mm=0;mm<32;mm++) h1[mm] = silu_q(fmaf(rij, Wj1[mm], bj1[mm]));
    float o = bj3[0];
    for (int n=0;n<32;n++) {
      float a2 = bj2[n];
      #pragma unroll
      for (int mm=0;mm<32;mm++) a2 = fmaf(h1[mm], Wj2[mm*32+n], a2);
      o = fmaf(silu_q(a2), Wj3[n], o);
    }
    jpart += o;
  }
  #pragma unroll
  for (int off=32; off>=1; off>>=1) jpart += __shfl_xor(jpart, off, 64);
  if ((t & 63) == 0) s_red[t >> 6] = jpart;

  // ---- stage 5+6: both spins' orbitals via f64 MFMA (LDS-staged f32 round),
  //      then ONE dual-spin interleaved LU (2 independent chains -> ILP). ----
  {
    const int g4 = wv * 4;
    const int g  = t >> 4;
    const int r  = t & 15;
    double a0r[16], a1r[16];

    // spin 0 orbital MFMA -> SORB
    __builtin_amdgcn_s_setprio(1);
    #pragma unroll 1
    for (int gi=0; gi<4; ++gi) {
      const int cb = (g4 + gi)*16 + lr;
      f64x4 ac = {0.0,0.0,0.0,0.0};
      #pragma unroll
      for (int kk=0;kk<16;kk++) {
        const int km = kk*4 + lq;
        ac = MFMA64((double)s_h[lr][km], (double)W_up[(size_t)km*256 + cb], ac);
      }
      const int row = lq*4;
      #pragma unroll
      for (int v=0;v<4;v++)
        SORB(row+v, cb) = (float)(ac[v] + (double)b_up[cb]);
    }
    __builtin_amdgcn_s_setprio(0);
    __syncthreads();
    #pragma unroll
    for (int j=0;j<16;j++) a0r[j] = (double)SORB(j, t);
    __syncthreads();

    // spin 1 orbital MFMA -> SORB
    __builtin_amdgcn_s_setprio(1);
    #pragma unroll 1
    for (int gi=0; gi<4; ++gi) {
      const int cb = (g4 + gi)*16 + lr;
      f64x4 ac = {0.0,0.0,0.0,0.0};
      #pragma unroll
      for (int kk=0;kk<16;kk++) {
        const int km = kk*4 + lq;
        ac = MFMA64((double)s_h[16+lr][km], (double)W_dn[(size_t)km*256 + cb], ac);
      }
      const int row = lq*4;
      #pragma unroll
      for (int v=0;v<4;v++)
        SORB(row+v, cb) = (float)(ac[v] + (double)b_dn[cb]);
    }
    __builtin_amdgcn_s_setprio(0);
    __syncthreads();
    #pragma unroll
    for (int j=0;j<16;j++) a1r[j] = (double)SORB(j, t);

    // --- dual-spin LU: operand-identical to R9's validated LU, two
    //     independent shuffle chains interleaved for latency hiding ---
    double prod0 = 1.0, prod1 = 1.0;
    int par0 = 0, par1 = 0;
    #pragma unroll
    for (int k=0;k<16;k++) {
      float bv0 = (r >= k) ? (float)fabs(a0r[k]) : -1.0f; int bi0 = r;
      float bv1 = (r >= k) ? (float)fabs(a1r[k]) : -1.0f; int bi1 = r;
      #pragma unroll
      for (int off=8; off>=1; off>>=1) {
        const float ov0 = __shfl_xor(bv0, off, 16); const int oi0 = __shfl_xor(bi0, off, 16);
        const float ov1 = __shfl_xor(bv1, off, 16); const int oi1 = __shfl_xor(bi1, off, 16);
        if (ov0 > bv0 || (ov0 == bv0 && oi0 < bi0)) { bv0 = ov0; bi0 = oi0; }
        if (ov1 > bv1 || (ov1 == bv1 && oi1 < bi1)) { bv1 = ov1; bi1 = oi1; }
      }
      const int p0 = bi0, p1 = bi1;
      par0 += (p0 != k) ? 1 : 0;
      par1 += (p1 != k) ? 1 : 0;
      const int src0 = (r == k) ? p0 : ((r == p0) ? k : r);
      const int src1 = (r == k) ? p1 : ((r == p1) ? k : r);
      const double piv0 = __shfl(a0r[k], p0, 16), nk0 = __shfl(a0r[k], src0, 16);
      const double piv1 = __shfl(a1r[k], p1, 16), nk1 = __shfl(a1r[k], src1, 16);
      prod0 *= piv0; prod1 *= piv1;
      const double f0 = (r > k && piv0 != 0.0) ? nk0/piv0 : 0.0;
      const double f1 = (r > k && piv1 != 0.0) ? nk1/piv1 : 0.0;
      a0r[k] = nk0; a1r[k] = nk1;
      #pragma unroll
      for (int j=k+1;j<16;j++) {
        const double sw0 = __shfl(a0r[j], src0, 16), kj0 = __shfl(a0r[j], p0, 16);
        const double sw1 = __shfl(a1r[j], src1, 16), kj1 = __shfl(a1r[j], p1, 16);
        a0r[j] = fma(-f0, kj0, sw0);
        a1r[j] = fma(-f1, kj1, sw1);
      }
    }
    if (r == 0) {
      s_lu[0][g] = log(fabs(prod0));
      s_su[0][g] = ((par0 + ((prod0 < 0.0) ? 1 : 0)) & 1) ? -1.f : 1.f;
      s_lu[1][g] = log(fabs(prod1));
      s_su[1][g] = ((par1 + ((prod1 < 0.0) ? 1 : 0)) & 1) ? -1.f : 1.f;
    }
  }
  __syncthreads();

  // ---- stage 7: signed logsumexp combine (f64, 16-thread parallel) ----
  if (t < 16) {
    const int k = t;
    const double wwk = (double)det_w[k];
    double mw = wwk;
    #pragma unroll
    for (int off=8; off>=1; off>>=1) mw = fmax(mw, __shfl_xor(mw, off, 16));
    const double ew = exp_d(wwk - mw);
    double sum = ew;
    #pragma unroll
    for (int off=8; off>=1; off>>=1) sum += __shfl_xor(sum, off, 16);
    const double lg = s_lu[0][k] + s_lu[1][k] + log(ew/sum + 1e-10);
    const double sg = (double)(s_su[0][k] * s_su[1][k]);
    double m2 = lg;
    #pragma unroll
    for (int off=8; off>=1; off>>=1) m2 = fmax(m2, __shfl_xor(m2, off, 16));
    double ssum = sg * exp_d(lg - m2);
    #pragma unroll
    for (int off=8; off>=1; off>>=1) ssum += __shfl_xor(ssum, off, 16);
    if (t == 0) {
      const double jas = (double)jscale[0] * (double)(s_red[0]+s_red[1]+s_red[2]+s_red[3]);
      out[w] = (float)(jas + m2 + log(fabs(ssum) + 1e-30));
      out[N_WALK + w] = (ssum > 0.0) ? 1.f : ((ssum < 0.0) ? -1.f : 0.f);
    }
  }
}

extern "C" void kernel_launch(void* const* d_in, const int* in_sizes, int n_in,
                              void* d_out, int out_size, void* d_ws, size_t ws_size,
                              hipStream_t stream) {
  const float* r_el  = (const float*)d_in[0];
  const float* cell  = (const float*)d_in[1];
  // d_in[2] = twist (unused by the reference)
  const float* W_e   = (const float*)d_in[3];
  const float* b_e   = (const float*)d_in[4];
  const float* W_pw  = (const float*)d_in[5];
  const float* b_pw  = (const float*)d_in[6];
  const float* W1    = (const float*)d_in[7];
  const float* b1    = (const float*)d_in[8];
  const float* W2    = (const float*)d_in[9];
  const float* b2    = (const float*)d_in[10];
  const float* ln_w  = (const float*)d_in[11];
  const float* ln_b  = (const float*)d_in[12];
  const float* W_up  = (const float*)d_in[13];
  const float* b_up  = (const float*)d_in[14];
  const float* W_dn  = (const float*)d_in[15];
  const float* b_dn  = (const float*)d_in[16];
  const float* det_w = (const float*)d_in[17];
  const float* Wj1   = (const float*)d_in[18];
  const float* bj1   = (const float*)d_in[19];
  const float* Wj2   = (const float*)d_in[20];
  const float* bj2   = (const float*)d_in[21];
  const float* Wj3   = (const float*)d_in[22];
  const float* bj3   = (const float*)d_in[23];
  const float* jsc   = (const float*)d_in[24];

  wf_kernel<<<N_WALK, 256, 0, stream>>>(
      r_el, cell, W_e, b_e, W_pw, b_pw, W1, b1, W2, b2, ln_w, ln_b,
      W_up, b_up, W_dn, b_dn, det_w, Wj1, bj1, Wj2, bj2, Wj3, bj3, jsc,
      (float*)d_out);
}

// Round 11
// 493.872 us; speedup vs baseline: 1.2335x; 1.2335x over previous
//
#include <hip/hip_runtime.h>

#define N_WALK 4096
#define N_EL   32
#define DIM    64
#define HPAD   68   // f32 row stride: 68%32=4 banks -> max 2-way conflict (free)
#define NLAY   3
#define KDET   16
#define NPAIR  496
#define TWO_PI_D 6.283185307179586476925286766559
#define JTAB_N    8192
#define JTAB_RMAX 5.25f

using f64x4 = __attribute__((ext_vector_type(4))) double;

#define MFMA64(A, B, C) __builtin_amdgcn_mfma_f64_16x16x4f64((A), (B), (C), 0, 0, 0)

// fast f64 exp, rel err ~3e-13 for |x| <= 60
__device__ __forceinline__ double exp_d(double x) {
  const double LOG2E  = 1.4426950408889634074;
  const double LN2_HI = 6.93147180369123816490e-01;
  const double LN2_LO = 1.90821492927058770002e-10;
  const double nf = rint(x * LOG2E);
  double r = fma(-nf, LN2_HI, x);
  r = fma(-nf, LN2_LO, r);
  double p = 1.0/3628800.0;
  p = fma(p, r, 1.0/362880.0);
  p = fma(p, r, 1.0/40320.0);
  p = fma(p, r, 1.0/5040.0);
  p = fma(p, r, 1.0/720.0);
  p = fma(p, r, 1.0/120.0);
  p = fma(p, r, 1.0/24.0);
  p = fma(p, r, 1.0/6.0);
  p = fma(p, r, 0.5);
  p = fma(p, r, 1.0);
  p = fma(p, r, 1.0);
  const long long bits = ((long long)((int)nf + 1023)) << 52;
  return p * __longlong_as_double(bits);
}

// silu with Newton-recip division (rel err ~1e-14)
__device__ __forceinline__ double silu_d(double x) {
  const double d = 1.0 + exp_d(-x);
  const double q0 = (double)(1.0f / (float)d);
  double q = q0 * (2.0 - d * q0);
  q = q * (2.0 - d * q);
  return x * q;
}
__device__ __forceinline__ float silu_q(float x) { return x / (1.0f + __expf(-x)); }

// ---- tiny pre-kernel: tabulate the scalar Jastrow MLP f(r) ----
__global__ __launch_bounds__(256) void jtab_kernel(
    const float* __restrict__ Wj1, const float* __restrict__ bj1,
    const float* __restrict__ Wj2, const float* __restrict__ bj2,
    const float* __restrict__ Wj3, const float* __restrict__ bj3,
    float* __restrict__ tab)
{
  const int i = blockIdx.x * 256 + threadIdx.x;
  if (i > JTAB_N) return;
  const float r = (float)i * (JTAB_RMAX / (float)JTAB_N);
  float h1[32];
  #pragma unroll
  for (int m=0;m<32;m++) h1[m] = silu_q(fmaf(r, Wj1[m], bj1[m]));
  float o = bj3[0];
  for (int n=0;n<32;n++) {
    float a2 = bj2[n];
    #pragma unroll
    for (int m=0;m<32;m++) a2 = fmaf(h1[m], Wj2[m*32+n], a2);
    o = fmaf(silu_q(a2), Wj3[n], o);
  }
  tab[i] = o;
}

__global__ __launch_bounds__(256) void wf_kernel(
    const float* __restrict__ r_el,
    const float* __restrict__ cell,
    const float* __restrict__ W_e,  const float* __restrict__ b_e,
    const float* __restrict__ W_pw, const float* __restrict__ b_pw,
    const float* __restrict__ W1,   const float* __restrict__ b1,
    const float* __restrict__ W2,   const float* __restrict__ b2,
    const float* __restrict__ ln_w, const float* __restrict__ ln_b,
    const float* __restrict__ W_up, const float* __restrict__ b_up,
    const float* __restrict__ W_dn, const float* __restrict__ b_dn,
    const float* __restrict__ det_w,
    const float* __restrict__ jtab,
    const float* __restrict__ jscale,
    float* __restrict__ out)
{
  __shared__ float s_linv[9];
  __shared__ float s_cl[9];
  __shared__ float s_r[N_EL][3];
  __shared__ float s_pw[N_EL][6];
  __shared__ float s_h[N_EL][HPAD];
  // union buffer: stage-3 s_y [32][HPAD]=2176 floats; stage-5 phi [16][257]=4112 floats
  __shared__ float s_u[16*257];
  __shared__ float s_hm[DIM];
  __shared__ double s_hb[DIM];        // b1 + hm @ W1[64:128]  (f64, per layer)
  __shared__ double s_lu[2][KDET];
  __shared__ float  s_su[2][KDET];
  __shared__ float  s_red[4];
#define SY(e,d)   s_u[(e)*HPAD + (d)]
#define SORB(j,c) s_u[(j)*257 + (c)]

  const int t = threadIdx.x;
  const int w = blockIdx.x;
  const int wv = t >> 6;         // wave id 0..3
  const int l  = t & 63;
  const int lr = l & 15;         // row/col fragment index
  const int lq = l >> 4;         // k fragment index

  // ---- cell inverse: f64 compute, f32 round ----
  if (t == 0) {
    double m00=cell[0], m01=cell[1], m02=cell[2];
    double m10=cell[3], m11=cell[4], m12=cell[5];
    double m20=cell[6], m21=cell[7], m22=cell[8];
    double c00 = m11*m22 - m12*m21;
    double c10 = m12*m20 - m10*m22;
    double c20 = m10*m21 - m11*m20;
    double det = m00*c00 + m01*c10 + m02*c20;
    double id = 1.0/det;
    s_linv[0]=(float)(c00*id); s_linv[1]=(float)((m02*m21-m01*m22)*id); s_linv[2]=(float)((m01*m12-m02*m11)*id);
    s_linv[3]=(float)(c10*id); s_linv[4]=(float)((m00*m22-m02*m20)*id); s_linv[5]=(float)((m02*m10-m00*m12)*id);
    s_linv[6]=(float)(c20*id); s_linv[7]=(float)((m01*m20-m00*m21)*id); s_linv[8]=(float)((m00*m11-m01*m10)*id);
    #pragma unroll
    for (int i=0;i<9;i++) s_cl[i]=cell[i];
  }
  __syncthreads();

  // ---- stage 1: wrap + plane waves (f64 dots, f32 tensor boundaries) ----
  if (t < N_EL) {
    const float* rp = r_el + ((size_t)w * N_EL + t) * 3;
    const float rx = rp[0], ry = rp[1], rz = rp[2];
    float s0 = (float)((double)s_linv[0]*rx + (double)s_linv[1]*ry + (double)s_linv[2]*rz);
    float s1 = (float)((double)s_linv[3]*rx + (double)s_linv[4]*ry + (double)s_linv[5]*rz);
    float s2 = (float)((double)s_linv[6]*rx + (double)s_linv[7]*ry + (double)s_linv[8]*rz);
    s0 -= floorf(s0); s1 -= floorf(s1); s2 -= floorf(s2);
    const float wx = (float)((double)s0*s_cl[0] + (double)s1*s_cl[3] + (double)s2*s_cl[6]);
    const float wy = (float)((double)s0*s_cl[1] + (double)s1*s_cl[4] + (double)s2*s_cl[7]);
    const float wz = (float)((double)s0*s_cl[2] + (double)s1*s_cl[5] + (double)s2*s_cl[8]);
    s_r[t][0]=wx; s_r[t][1]=wy; s_r[t][2]=wz;
    const float u0 = (float)((double)s_linv[0]*wx + (double)s_linv[1]*wy + (double)s_linv[2]*wz);
    const float u1 = (float)((double)s_linv[3]*wx + (double)s_linv[4]*wy + (double)s_linv[5]*wz);
    const float u2 = (float)((double)s_linv[6]*wx + (double)s_linv[7]*wy + (double)s_linv[8]*wz);
    double sn, cs;
    sincos(TWO_PI_D*(double)u0, &sn, &cs); s_pw[t][0]=(float)sn; s_pw[t][3]=(float)cs;
    sincos(TWO_PI_D*(double)u1, &sn, &cs); s_pw[t][1]=(float)sn; s_pw[t][4]=(float)cs;
    sincos(TWO_PI_D*(double)u2, &sn, &cs); s_pw[t][2]=(float)sn; s_pw[t][5]=(float)cs;
  }
  __syncthreads();

  // ---- stage 2: h0 (f64 acc -> f32 store) ----
  {
    const int e = t >> 3, db = (t & 7) * 8;
    const double rx=s_r[e][0], ry=s_r[e][1], rz=s_r[e][2];
    const double p0=s_pw[e][0],p1=s_pw[e][1],p2=s_pw[e][2];
    const double p3=s_pw[e][3],p4=s_pw[e][4],p5=s_pw[e][5];
    #pragma unroll
    for (int u=0;u<8;u++) {
      const int d = db+u;
      double acc = (double)b_e[d] + (double)b_pw[d];
      acc = fma(rx, (double)W_e[0*DIM+d], acc);
      acc = fma(ry, (double)W_e[1*DIM+d], acc);
      acc = fma(rz, (double)W_e[2*DIM+d], acc);
      acc = fma(p0, (double)W_pw[0*DIM+d], acc);
      acc = fma(p1, (double)W_pw[1*DIM+d], acc);
      acc = fma(p2, (double)W_pw[2*DIM+d], acc);
      acc = fma(p3, (double)W_pw[3*DIM+d], acc);
      acc = fma(p4, (double)W_pw[4*DIM+d], acc);
      acc = fma(p5, (double)W_pw[5*DIM+d], acc);
      s_h[e][d] = (float)acc;
    }
  }
  __syncthreads();

  const int m  = wv & 1;
  const int nb = (wv >> 1) * 2;
  const int ea = m*16 + lr;        // A-fragment row (electron)
  const int c0 = nb*16 + lr;       // D/B column of tile 0 (tile 1 = c0+16)
  const int er = m*16 + lq*4;      // D row base

  // ---- stage 3: interaction layers via f64 MFMA ----
  for (int L = 0; L < NLAY; ++L) {
    const float* __restrict__ w1p = W1 + (size_t)L*192*DIM;
    const float* __restrict__ w2p = W2 + (size_t)L*DIM*DIM;

    // hm (f32 tensor) + hb = b1 + hm @ W1[64:128] (f64 rank-1 hoist), wave 0.
    if (t < DIM) {
      double s = 0.0;
      #pragma unroll 8
      for (int e=0;e<N_EL;e++) s += (double)s_h[e][t];
      const float hmf = (float)(s * (1.0/N_EL));
      s_hm[t] = hmf;
      double hb = (double)b1[L*DIM + t];
      #pragma unroll 8
      for (int km=0;km<DIM;km++)
        hb = fma((double)s_hm[km], (double)w1p[(64+km)*DIM + t], hb);
      s_hb[t] = hb;
    }
    __syncthreads();

    // --- y = silu(h@W1a + (h*hm)@W1c + hb) ---
    {
      f64x4 a0 = {0.0,0.0,0.0,0.0}, a1 = {0.0,0.0,0.0,0.0};
      #pragma unroll
      for (int kk=0;kk<16;kk++) {              // K seg 0: x = h
        const int km = kk*4 + lq;
        const double af = (double)s_h[ea][km];
        const double q0 = (double)w1p[km*DIM + c0];
        const double q1 = (double)w1p[km*DIM + c0 + 16];
        a0 = MFMA64(af, q0, a0);
        a1 = MFMA64(af, q1, a1);
      }
      #pragma unroll
      for (int kk=0;kk<16;kk++) {              // K seg 2: x = h*hm (f32 product)
        const int km = kk*4 + lq;
        const double af = (double)(s_h[ea][km] * s_hm[km]);
        const double q0 = (double)w1p[(128+km)*DIM + c0];
        const double q1 = (double)w1p[(128+km)*DIM + c0 + 16];
        a0 = MFMA64(af, q0, a0);
        a1 = MFMA64(af, q1, a1);
      }
      #pragma unroll
      for (int v=0;v<4;v++) {
        const float p0 = (float)(a0[v] + s_hb[c0]);        // np pre-act (f64 reorder)
        const float p1 = (float)(a1[v] + s_hb[c0 + 16]);
        SY(er+v, c0)      = (float)silu_d((double)p0);
        SY(er+v, c0 + 16) = (float)silu_d((double)p1);
      }
    }
    __syncthreads();

    // --- delta = y @ W2 + b2 ; v = h + delta written DIRECTLY to s_h ---
    {
      f64x4 a0 = {0.0,0.0,0.0,0.0}, a1 = {0.0,0.0,0.0,0.0};
      #pragma unroll
      for (int kk=0;kk<16;kk++) {
        const int km = kk*4 + lq;
        const double af = (double)SY(ea, km);
        const double q0 = (double)w2p[km*DIM + c0];
        const double q1 = (double)w2p[km*DIM + c0 + 16];
        a0 = MFMA64(af, q0, a0);
        a1 = MFMA64(af, q1, a1);
      }
      #pragma unroll
      for (int v=0;v<4;v++) {
        const float d0 = (float)(a0[v] + (double)b2[L*DIM + c0]);      // np delta
        const float d1 = (float)(a1[v] + (double)b2[L*DIM + c0 + 16]);
        s_h[er+v][c0]      = s_h[er+v][c0]      + d0;                  // np h+delta
        s_h[er+v][c0 + 16] = s_h[er+v][c0 + 16] + d1;
      }
    }
    __syncthreads();

    // --- LayerNorm: stats f64 (Newton rstd), reads v from s_h, writes s_h ---
    {
      const int e = t >> 3, db = (t & 7) * 8;
      float v[8];
      double ps=0.0, pss=0.0;
      #pragma unroll
      for (int u=0;u<8;u++) {
        v[u] = s_h[e][db+u];
        ps += (double)v[u]; pss += (double)v[u]*(double)v[u];
      }
      #pragma unroll
      for (int off=4; off>=1; off>>=1) {
        ps  += __shfl_xor(ps,  off, 8);
        pss += __shfl_xor(pss, off, 8);
      }
      const double mu = ps * (1.0/DIM);
      double var = pss * (1.0/DIM) - mu*mu;
      var = fmax(var, 0.0);
      const double s = var + 1e-5;
      double rstd = (double)rsqrtf((float)s);
      rstd = rstd * (1.5 - 0.5*s*rstd*rstd);
      rstd = rstd * (1.5 - 0.5*s*rstd*rstd);
      #pragma unroll
      for (int u=0;u<8;u++) {
        const int d = db+u;
        s_h[e][d] = (float)(((double)v[u]-mu)*rstd*(double)ln_w[L*DIM+d] + (double)ln_b[L*DIM+d]);
      }
    }
    __syncthreads();
  }

  // ---- stage 4: Jastrow via table lookup (geometry exact, f(r) tabulated;
  //      per-pair err ~1e-6, total ~1e-4 into log_psi — negligible). ----
  float jpart = 0.f;
  for (int p = t; p < NPAIR; p += 256) {
    int i = 0, rem = p;
    while (rem >= (N_EL-1) - i) { rem -= (N_EL-1) - i; ++i; }
    const int j = i + 1 + rem;
    const float dx = s_r[i][0]-s_r[j][0];
    const float dy = s_r[i][1]-s_r[j][1];
    const float dz = s_r[i][2]-s_r[j][2];
    float q0 = (float)((double)s_linv[0]*dx + (double)s_linv[1]*dy + (double)s_linv[2]*dz);
    float q1 = (float)((double)s_linv[3]*dx + (double)s_linv[4]*dy + (double)s_linv[5]*dz);
    float q2 = (float)((double)s_linv[6]*dx + (double)s_linv[7]*dy + (double)s_linv[8]*dz);
    q0 -= rintf(q0); q1 -= rintf(q1); q2 -= rintf(q2);
    const float vx = (float)((double)q0*s_cl[0] + (double)q1*s_cl[3] + (double)q2*s_cl[6]);
    const float vy = (float)((double)q0*s_cl[1] + (double)q1*s_cl[4] + (double)q2*s_cl[7]);
    const float vz = (float)((double)q0*s_cl[2] + (double)q1*s_cl[5] + (double)q2*s_cl[8]);
    const float rij = sqrtf(vx*vx + vy*vy + vz*vz);
    const float u = rij * ((float)JTAB_N / JTAB_RMAX);
    int i0 = (int)u;
    i0 = (i0 > JTAB_N-1) ? (JTAB_N-1) : i0;
    const float fr = u - (float)i0;
    const float f0 = jtab[i0], f1 = jtab[i0+1];
    jpart += fmaf(fr, f1 - f0, f0);
  }
  #pragma unroll
  for (int off=32; off>=1; off>>=1) jpart += __shfl_xor(jpart, off, 64);
  if ((t & 63) == 0) s_red[t >> 6] = jpart;

  // ---- stage 5+6: both spins' orbitals via f64 MFMA (LDS-staged f32 round),
  //      then dual-spin interleaved LU. NO barriers: each wave reads back
  //      exactly the SORB columns it wrote (cols 64wv..64wv+63); same-wave
  //      DS ordering guarantees correctness. ----
  {
    const int g4 = wv * 4;
    const int g  = t >> 4;
    const int r  = t & 15;
    double a0r[16], a1r[16];

    __builtin_amdgcn_s_setprio(1);
    #pragma unroll 1
    for (int gi=0; gi<4; ++gi) {               // spin 0 -> SORB
      const int cb = (g4 + gi)*16 + lr;
      f64x4 ac = {0.0,0.0,0.0,0.0};
      #pragma unroll
      for (int kk=0;kk<16;kk++) {
        const int km = kk*4 + lq;
        ac = MFMA64((double)s_h[lr][km], (double)W_up[(size_t)km*256 + cb], ac);
      }
      const int row = lq*4;
      #pragma unroll
      for (int v=0;v<4;v++)
        SORB(row+v, cb) = (float)(ac[v] + (double)b_up[cb]);
    }
    __builtin_amdgcn_s_setprio(0);
    #pragma unroll
    for (int j=0;j<16;j++) a0r[j] = (double)SORB(j, t);

    __builtin_amdgcn_s_setprio(1);
    #pragma unroll 1
    for (int gi=0; gi<4; ++gi) {               // spin 1 -> SORB (same region)
      const int cb = (g4 + gi)*16 + lr;
      f64x4 ac = {0.0,0.0,0.0,0.0};
      #pragma unroll
      for (int kk=0;kk<16;kk++) {
        const int km = kk*4 + lq;
        ac = MFMA64((double)s_h[16+lr][km], (double)W_dn[(size_t)km*256 + cb], ac);
      }
      const int row = lq*4;
      #pragma unroll
      for (int v=0;v<4;v++)
        SORB(row+v, cb) = (float)(ac[v] + (double)b_dn[cb]);
    }
    __builtin_amdgcn_s_setprio(0);
    #pragma unroll
    for (int j=0;j<16;j++) a1r[j] = (double)SORB(j, t);

    // --- dual-spin LU: operand-identical to R9/R10's validated LU ---
    double prod0 = 1.0, prod1 = 1.0;
    int par0 = 0, par1 = 0;
    #pragma unroll
    for (int k=0;k<16;k++) {
      float bv0 = (r >= k) ? (float)fabs(a0r[k]) : -1.0f; int bi0 = r;
      float bv1 = (r >= k) ? (float)fabs(a1r[k]) : -1.0f; int bi1 = r;
      #pragma unroll
      for (int off=8; off>=1; off>>=1) {
        const float ov0 = __shfl_xor(bv0, off, 16); const int oi0 = __shfl_xor(bi0, off, 16);
        const float ov1 = __shfl_xor(bv1, off, 16); const int oi1 = __shfl_xor(bi1, off, 16);
        if (ov0 > bv0 || (ov0 == bv0 && oi0 < bi0)) { bv0 = ov0; bi0 = oi0; }
        if (ov1 > bv1 || (ov1 == bv1 && oi1 < bi1)) { bv1 = ov1; bi1 = oi1; }
      }
      const int p0 = bi0, p1 = bi1;
      par0 += (p0 != k) ? 1 : 0;
      par1 += (p1 != k) ? 1 : 0;
      const int src0 = (r == k) ? p0 : ((r == p0) ? k : r);
      const int src1 = (r == k) ? p1 : ((r == p1) ? k : r);
      const double piv0 = __shfl(a0r[k], p0, 16), nk0 = __shfl(a0r[k], src0, 16);
      const double piv1 = __shfl(a1r[k], p1, 16), nk1 = __shfl(a1r[k], src1, 16);
      prod0 *= piv0; prod1 *= piv1;
      const double f0 = (r > k && piv0 != 0.0) ? nk0/piv0 : 0.0;
      const double f1 = (r > k && piv1 != 0.0) ? nk1/piv1 : 0.0;
      a0r[k] = nk0; a1r[k] = nk1;
      #pragma unroll
      for (int j=k+1;j<16;j++) {
        const double sw0 = __shfl(a0r[j], src0, 16), kj0 = __shfl(a0r[j], p0, 16);
        const double sw1 = __shfl(a1r[j], src1, 16), kj1 = __shfl(a1r[j], p1, 16);
        a0r[j] = fma(-f0, kj0, sw0);
        a1r[j] = fma(-f1, kj1, sw1);
      }
    }
    if (r == 0) {
      s_lu[0][g] = log(fabs(prod0));
      s_su[0][g] = ((par0 + ((prod0 < 0.0) ? 1 : 0)) & 1) ? -1.f : 1.f;
      s_lu[1][g] = log(fabs(prod1));
      s_su[1][g] = ((par1 + ((prod1 < 0.0) ? 1 : 0)) & 1) ? -1.f : 1.f;
    }
  }
  __syncthreads();

  // ---- stage 7: signed logsumexp combine (f64, 16-thread parallel) ----
  if (t < 16) {
    const int k = t;
    const double wwk = (double)det_w[k];
    double mw = wwk;
    #pragma unroll
    for (int off=8; off>=1; off>>=1) mw = fmax(mw, __shfl_xor(mw, off, 16));
    const double ew = exp_d(wwk - mw);
    double sum = ew;
    #pragma unroll
    for (int off=8; off>=1; off>>=1) sum += __shfl_xor(sum, off, 16);
    const double lg = s_lu[0][k] + s_lu[1][k] + log(ew/sum + 1e-10);
    const double sg = (double)(s_su[0][k] * s_su[1][k]);
    double m2 = lg;
    #pragma unroll
    for (int off=8; off>=1; off>>=1) m2 = fmax(m2, __shfl_xor(m2, off, 16));
    double ssum = sg * exp_d(lg - m2);
    #pragma unroll
    for (int off=8; off>=1; off>>=1) ssum += __shfl_xor(ssum, off, 16);
    if (t == 0) {
      const double jas = (double)jscale[0] * (double)(s_red[0]+s_red[1]+s_red[2]+s_red[3]);
      out[w] = (float)(jas + m2 + log(fabs(ssum) + 1e-30));
      out[N_WALK + w] = (ssum > 0.0) ? 1.f : ((ssum < 0.0) ? -1.f : 0.f);
    }
  }
}

extern "C" void kernel_launch(void* const* d_in, const int* in_sizes, int n_in,
                              void* d_out, int out_size, void* d_ws, size_t ws_size,
                              hipStream_t stream) {
  const float* r_el  = (const float*)d_in[0];
  const float* cell  = (const float*)d_in[1];
  // d_in[2] = twist (unused by the reference)
  const float* W_e   = (const float*)d_in[3];
  const float* b_e   = (const float*)d_in[4];
  const float* W_pw  = (const float*)d_in[5];
  const float* b_pw  = (const float*)d_in[6];
  const float* W1    = (const float*)d_in[7];
  const float* b1    = (const float*)d_in[8];
  const float* W2    = (const float*)d_in[9];
  const float* b2    = (const float*)d_in[10];
  const float* ln_w  = (const float*)d_in[11];
  const float* ln_b  = (const float*)d_in[12];
  const float* W_up  = (const float*)d_in[13];
  const float* b_up  = (const float*)d_in[14];
  const float* W_dn  = (const float*)d_in[15];
  const float* b_dn  = (const float*)d_in[16];
  const float* det_w = (const float*)d_in[17];
  const float* Wj1   = (const float*)d_in[18];
  const float* bj1   = (const float*)d_in[19];
  const float* Wj2   = (const float*)d_in[20];
  const float* bj2   = (const float*)d_in[21];
  const float* Wj3   = (const float*)d_in[22];
  const float* bj3   = (const float*)d_in[23];
  const float* jsc   = (const float*)d_in[24];
  float* jtab = (float*)d_ws;    // (JTAB_N+1) floats = 32.8 KB scratch

  jtab_kernel<<<(JTAB_N + 1 + 255) / 256, 256, 0, stream>>>(
      Wj1, bj1, Wj2, bj2, Wj3, bj3, jtab);

  wf_kernel<<<N_WALK, 256, 0, stream>>>(
      r_el, cell, W_e, b_e, W_pw, b_pw, W1, b1, W2, b2, ln_w, ln_b,
      W_up, b_up, W_dn, b_dn, det_w, jtab, jsc,
      (float*)d_out);
}

// Round 12
// 483.760 us; speedup vs baseline: 1.2593x; 1.0209x over previous
//
#include <hip/hip_runtime.h>

#define N_WALK 4096
#define N_EL   32
#define DIM    64
#define HPAD   66   // f32 row stride: 66%32=2 -> 16 distinct banks for row-indexed reads
#define NLAY   3
#define KDET   16
#define NPAIR  496
#define TWO_PI_D 6.283185307179586476925286766559
#define JTAB_N    8192
#define JTAB_RMAX 5.25f

using f64x4 = __attribute__((ext_vector_type(4))) double;

#define MFMA64(A, B, C) __builtin_amdgcn_mfma_f64_16x16x4f64((A), (B), (C), 0, 0, 0)

// fast f64 exp, rel err ~3e-13 for |x| <= 60
__device__ __forceinline__ double exp_d(double x) {
  const double LOG2E  = 1.4426950408889634074;
  const double LN2_HI = 6.93147180369123816490e-01;
  const double LN2_LO = 1.90821492927058770002e-10;
  const double nf = rint(x * LOG2E);
  double r = fma(-nf, LN2_HI, x);
  r = fma(-nf, LN2_LO, r);
  double p = 1.0/3628800.0;
  p = fma(p, r, 1.0/362880.0);
  p = fma(p, r, 1.0/40320.0);
  p = fma(p, r, 1.0/5040.0);
  p = fma(p, r, 1.0/720.0);
  p = fma(p, r, 1.0/120.0);
  p = fma(p, r, 1.0/24.0);
  p = fma(p, r, 1.0/6.0);
  p = fma(p, r, 0.5);
  p = fma(p, r, 1.0);
  p = fma(p, r, 1.0);
  const long long bits = ((long long)((int)nf + 1023)) << 52;
  return p * __longlong_as_double(bits);
}

// silu with Newton-recip division (rel err ~1e-14)
__device__ __forceinline__ double silu_d(double x) {
  const double d = 1.0 + exp_d(-x);
  const double q0 = (double)(1.0f / (float)d);
  double q = q0 * (2.0 - d * q0);
  q = q * (2.0 - d * q);
  return x * q;
}
__device__ __forceinline__ float silu_q(float x) { return x / (1.0f + __expf(-x)); }

// ---- tiny pre-kernel: tabulate the scalar Jastrow MLP f(r) ----
__global__ __launch_bounds__(256) void jtab_kernel(
    const float* __restrict__ Wj1, const float* __restrict__ bj1,
    const float* __restrict__ Wj2, const float* __restrict__ bj2,
    const float* __restrict__ Wj3, const float* __restrict__ bj3,
    float* __restrict__ tab)
{
  const int i = blockIdx.x * 256 + threadIdx.x;
  if (i > JTAB_N) return;
  const float r = (float)i * (JTAB_RMAX / (float)JTAB_N);
  float h1[32];
  #pragma unroll
  for (int m=0;m<32;m++) h1[m] = silu_q(fmaf(r, Wj1[m], bj1[m]));
  float o = bj3[0];
  for (int n=0;n<32;n++) {
    float a2 = bj2[n];
    #pragma unroll
    for (int m=0;m<32;m++) a2 = fmaf(h1[m], Wj2[m*32+n], a2);
    o = fmaf(silu_q(a2), Wj3[n], o);
  }
  tab[i] = o;
}

__global__ __launch_bounds__(256) void wf_kernel(
    const float* __restrict__ r_el,
    const float* __restrict__ cell,
    const float* __restrict__ W_e,  const float* __restrict__ b_e,
    const float* __restrict__ W_pw, const float* __restrict__ b_pw,
    const float* __restrict__ W1,   const float* __restrict__ b1,
    const float* __restrict__ W2,   const float* __restrict__ b2,
    const float* __restrict__ ln_w, const float* __restrict__ ln_b,
    const float* __restrict__ W_up, const float* __restrict__ b_up,
    const float* __restrict__ W_dn, const float* __restrict__ b_dn,
    const float* __restrict__ det_w,
    const float* __restrict__ jtab,
    const float* __restrict__ jscale,
    float* __restrict__ out)
{
  __shared__ float s_linv[9];
  __shared__ float s_cl[9];
  __shared__ float s_r[N_EL][3];
  __shared__ float s_h[N_EL][HPAD];
  // union buffer: SY [32][66]=2112 | s_pw at [2112,2304) | SORB [16][257]=4112
  __shared__ float s_u[16*257];
  __shared__ float s_hm[DIM];
  __shared__ double s_hb[DIM];        // b1 + hm @ W1[64:128]  (f64, per layer)
  __shared__ double s_lu[2][KDET];
  __shared__ float  s_su[2][KDET];
  __shared__ float  s_red[4];
#define SY(e,d)   s_u[(e)*HPAD + (d)]
#define SPW(e,i)  s_u[2112 + (e)*6 + (i)]
#define SORB(j,c) s_u[(j)*257 + (c)]

  const int t = threadIdx.x;
  const int w = blockIdx.x;
  const int wv = t >> 6;         // wave id 0..3
  const int l  = t & 63;
  const int lr = l & 15;         // row/col fragment index
  const int lq = l >> 4;         // k fragment index

  // ---- cell inverse: f64 compute, f32 round ----
  if (t == 0) {
    double m00=cell[0], m01=cell[1], m02=cell[2];
    double m10=cell[3], m11=cell[4], m12=cell[5];
    double m20=cell[6], m21=cell[7], m22=cell[8];
    double c00 = m11*m22 - m12*m21;
    double c10 = m12*m20 - m10*m22;
    double c20 = m10*m21 - m11*m20;
    double det = m00*c00 + m01*c10 + m02*c20;
    double id = 1.0/det;
    s_linv[0]=(float)(c00*id); s_linv[1]=(float)((m02*m21-m01*m22)*id); s_linv[2]=(float)((m01*m12-m02*m11)*id);
    s_linv[3]=(float)(c10*id); s_linv[4]=(float)((m00*m22-m02*m20)*id); s_linv[5]=(float)((m02*m10-m00*m12)*id);
    s_linv[6]=(float)(c20*id); s_linv[7]=(float)((m01*m20-m00*m21)*id); s_linv[8]=(float)((m00*m11-m01*m10)*id);
    #pragma unroll
    for (int i=0;i<9;i++) s_cl[i]=cell[i];
  }
  __syncthreads();

  // ---- stage 1a: wrap (f64 dots, f32 boundaries); store u (f32 tensor) ----
  if (t < N_EL) {
    const float* rp = r_el + ((size_t)w * N_EL + t) * 3;
    const float rx = rp[0], ry = rp[1], rz = rp[2];
    float s0 = (float)((double)s_linv[0]*rx + (double)s_linv[1]*ry + (double)s_linv[2]*rz);
    float s1 = (float)((double)s_linv[3]*rx + (double)s_linv[4]*ry + (double)s_linv[5]*rz);
    float s2 = (float)((double)s_linv[6]*rx + (double)s_linv[7]*ry + (double)s_linv[8]*rz);
    s0 -= floorf(s0); s1 -= floorf(s1); s2 -= floorf(s2);
    const float wx = (float)((double)s0*s_cl[0] + (double)s1*s_cl[3] + (double)s2*s_cl[6]);
    const float wy = (float)((double)s0*s_cl[1] + (double)s1*s_cl[4] + (double)s2*s_cl[7]);
    const float wz = (float)((double)s0*s_cl[2] + (double)s1*s_cl[5] + (double)s2*s_cl[8]);
    s_r[t][0]=wx; s_r[t][1]=wy; s_r[t][2]=wz;
    SPW(t,0) = (float)((double)s_linv[0]*wx + (double)s_linv[1]*wy + (double)s_linv[2]*wz);
    SPW(t,1) = (float)((double)s_linv[3]*wx + (double)s_linv[4]*wy + (double)s_linv[5]*wz);
    SPW(t,2) = (float)((double)s_linv[6]*wx + (double)s_linv[7]*wy + (double)s_linv[8]*wz);
  }
  __syncthreads();

  // ---- stage 1b: plane waves, one sincos per (electron, axis) ----
  if (t < 128) {
    const int e = t >> 2, ax = t & 3;
    if (ax < 3) {
      const float u = SPW(e, ax);
      double sn, cs;
      sincos(TWO_PI_D*(double)u, &sn, &cs);
      SPW(e, ax)   = (float)sn;
      SPW(e, ax+3) = (float)cs;
    }
  }
  __syncthreads();

  // ---- stage 2: h0 (f64 acc -> f32 store) ----
  {
    const int e = t >> 3, db = (t & 7) * 8;
    const double rx=s_r[e][0], ry=s_r[e][1], rz=s_r[e][2];
    const double p0=SPW(e,0),p1=SPW(e,1),p2=SPW(e,2);
    const double p3=SPW(e,3),p4=SPW(e,4),p5=SPW(e,5);
    #pragma unroll
    for (int u=0;u<8;u++) {
      const int d = db+u;
      double acc = (double)b_e[d] + (double)b_pw[d];
      acc = fma(rx, (double)W_e[0*DIM+d], acc);
      acc = fma(ry, (double)W_e[1*DIM+d], acc);
      acc = fma(rz, (double)W_e[2*DIM+d], acc);
      acc = fma(p0, (double)W_pw[0*DIM+d], acc);
      acc = fma(p1, (double)W_pw[1*DIM+d], acc);
      acc = fma(p2, (double)W_pw[2*DIM+d], acc);
      acc = fma(p3, (double)W_pw[3*DIM+d], acc);
      acc = fma(p4, (double)W_pw[4*DIM+d], acc);
      acc = fma(p5, (double)W_pw[5*DIM+d], acc);
      s_h[e][d] = (float)acc;
    }
  }
  __syncthreads();

  const int m  = wv & 1;
  const int nb = (wv >> 1) * 2;
  const int ea = m*16 + lr;        // A-fragment row (electron)
  const int c0 = nb*16 + lr;       // D/B column of tile 0 (tile 1 = c0+16)
  const int er = m*16 + lq*4;      // D row base

  // ---- stage 3: interaction layers via f64 MFMA ----
  for (int L = 0; L < NLAY; ++L) {
    const float* __restrict__ w1p = W1 + (size_t)L*192*DIM;
    const float* __restrict__ w2p = W2 + (size_t)L*DIM*DIM;

    // Per-wave prologue, NO barrier:
    //  hm: every wave computes all 64 entries (bitwise-identical across waves
    //  -> benign race; wave-internal lgkmcnt orders write->read).
    //  hb (own 32 cols): 2 lanes/col halves, combined via shfl (f64 order
    //  change only — f32 boundaries unaffected).
    {
      double s = 0.0;
      #pragma unroll 8
      for (int e=0;e<N_EL;e++) s += (double)s_h[e][l];
      s_hm[l] = (float)(s * (1.0/N_EL));
      const int c = nb*16 + (l & 31);
      const int half = l >> 5;
      double hb = (half == 0) ? (double)b1[L*DIM + c] : 0.0;
      const int k0 = half*32;
      #pragma unroll 8
      for (int km=k0; km<k0+32; km++)
        hb = fma((double)s_hm[km], (double)w1p[(64+km)*DIM + c], hb);
      hb += __shfl_xor(hb, 32, 64);
      if (half == 0) s_hb[c] = hb;
    }

    // --- y = silu(h@W1a + (h*hm)@W1c + hb) ---
    {
      f64x4 a0 = {0.0,0.0,0.0,0.0}, a1 = {0.0,0.0,0.0,0.0};
      #pragma unroll
      for (int kk=0;kk<16;kk++) {              // K seg 0: x = h
        const int km = kk*4 + lq;
        const double af = (double)s_h[ea][km];
        const double q0 = (double)w1p[km*DIM + c0];
        const double q1 = (double)w1p[km*DIM + c0 + 16];
        a0 = MFMA64(af, q0, a0);
        a1 = MFMA64(af, q1, a1);
      }
      #pragma unroll
      for (int kk=0;kk<16;kk++) {              // K seg 2: x = h*hm (f32 product)
        const int km = kk*4 + lq;
        const double af = (double)(s_h[ea][km] * s_hm[km]);
        const double q0 = (double)w1p[(128+km)*DIM + c0];
        const double q1 = (double)w1p[(128+km)*DIM + c0 + 16];
        a0 = MFMA64(af, q0, a0);
        a1 = MFMA64(af, q1, a1);
      }
      #pragma unroll
      for (int v=0;v<4;v++) {
        const float p0 = (float)(a0[v] + s_hb[c0]);        // np pre-act (f64 reorder)
        const float p1 = (float)(a1[v] + s_hb[c0 + 16]);
        SY(er+v, c0)      = (float)silu_d((double)p0);
        SY(er+v, c0 + 16) = (float)silu_d((double)p1);
      }
    }
    __syncthreads();

    // --- delta = y @ W2 + b2 ; v = h + delta written DIRECTLY to s_h ---
    {
      f64x4 a0 = {0.0,0.0,0.0,0.0}, a1 = {0.0,0.0,0.0,0.0};
      #pragma unroll
      for (int kk=0;kk<16;kk++) {
        const int km = kk*4 + lq;
        const double af = (double)SY(ea, km);
        const double q0 = (double)w2p[km*DIM + c0];
        const double q1 = (double)w2p[km*DIM + c0 + 16];
        a0 = MFMA64(af, q0, a0);
        a1 = MFMA64(af, q1, a1);
      }
      #pragma unroll
      for (int v=0;v<4;v++) {
        const float d0 = (float)(a0[v] + (double)b2[L*DIM + c0]);      // np delta
        const float d1 = (float)(a1[v] + (double)b2[L*DIM + c0 + 16]);
        s_h[er+v][c0]      = s_h[er+v][c0]      + d0;                  // np h+delta
        s_h[er+v][c0 + 16] = s_h[er+v][c0 + 16] + d1;
      }
    }
    __syncthreads();

    // --- LayerNorm: stats f64 (Newton rstd), reads v from s_h, writes s_h ---
    {
      const int e = t >> 3, db = (t & 7) * 8;
      float v[8];
      double ps=0.0, pss=0.0;
      #pragma unroll
      for (int u=0;u<8;u++) {
        v[u] = s_h[e][db+u];
        ps += (double)v[u]; pss += (double)v[u]*(double)v[u];
      }
      #pragma unroll
      for (int off=4; off>=1; off>>=1) {
        ps  += __shfl_xor(ps,  off, 8);
        pss += __shfl_xor(pss, off, 8);
      }
      const double mu = ps * (1.0/DIM);
      double var = pss * (1.0/DIM) - mu*mu;
      var = fmax(var, 0.0);
      const double s = var + 1e-5;
      double rstd = (double)rsqrtf((float)s);
      rstd = rstd * (1.5 - 0.5*s*rstd*rstd);
      rstd = rstd * (1.5 - 0.5*s*rstd*rstd);
      #pragma unroll
      for (int u=0;u<8;u++) {
        const int d = db+u;
        s_h[e][d] = (float)(((double)v[u]-mu)*rstd*(double)ln_w[L*DIM+d] + (double)ln_b[L*DIM+d]);
      }
    }
    __syncthreads();
  }

  // ---- stage 4: Jastrow via table lookup ----
  float jpart = 0.f;
  for (int p = t; p < NPAIR; p += 256) {
    int i = 0, rem = p;
    while (rem >= (N_EL-1) - i) { rem -= (N_EL-1) - i; ++i; }
    const int j = i + 1 + rem;
    const float dx = s_r[i][0]-s_r[j][0];
    const float dy = s_r[i][1]-s_r[j][1];
    const float dz = s_r[i][2]-s_r[j][2];
    float q0 = (float)((double)s_linv[0]*dx + (double)s_linv[1]*dy + (double)s_linv[2]*dz);
    float q1 = (float)((double)s_linv[3]*dx + (double)s_linv[4]*dy + (double)s_linv[5]*dz);
    float q2 = (float)((double)s_linv[6]*dx + (double)s_linv[7]*dy + (double)s_linv[8]*dz);
    q0 -= rintf(q0); q1 -= rintf(q1); q2 -= rintf(q2);
    const float vx = (float)((double)q0*s_cl[0] + (double)q1*s_cl[3] + (double)q2*s_cl[6]);
    const float vy = (float)((double)q0*s_cl[1] + (double)q1*s_cl[4] + (double)q2*s_cl[7]);
    const float vz = (float)((double)q0*s_cl[2] + (double)q1*s_cl[5] + (double)q2*s_cl[8]);
    const float rij = sqrtf(vx*vx + vy*vy + vz*vz);
    const float u = rij * ((float)JTAB_N / JTAB_RMAX);
    int i0 = (int)u;
    i0 = (i0 > JTAB_N-1) ? (JTAB_N-1) : i0;
    const float fr = u - (float)i0;
    const float f0 = jtab[i0], f1 = jtab[i0+1];
    jpart += fmaf(fr, f1 - f0, f0);
  }
  #pragma unroll
  for (int off=32; off>=1; off>>=1) jpart += __shfl_xor(jpart, off, 64);
  if ((t & 63) == 0) s_red[t >> 6] = jpart;

  // ---- stage 5+6: both spins' orbitals via f64 MFMA (LDS-staged f32 round),
  //      then dual-spin interleaved LU. No barriers (wave-private SORB slab).
  {
    const int g4 = wv * 4;
    const int g  = t >> 4;
    const int r  = t & 15;
    double a0r[16], a1r[16];

    __builtin_amdgcn_s_setprio(1);
    #pragma unroll 1
    for (int gi=0; gi<4; ++gi) {               // spin 0 -> SORB
      const int cb = (g4 + gi)*16 + lr;
      f64x4 ac = {0.0,0.0,0.0,0.0};
      #pragma unroll
      for (int kk=0;kk<16;kk++) {
        const int km = kk*4 + lq;
        ac = MFMA64((double)s_h[lr][km], (double)W_up[(size_t)km*256 + cb], ac);
      }
      const int row = lq*4;
      #pragma unroll
      for (int v=0;v<4;v++)
        SORB(row+v, cb) = (float)(ac[v] + (double)b_up[cb]);
    }
    __builtin_amdgcn_s_setprio(0);
    #pragma unroll
    for (int j=0;j<16;j++) a0r[j] = (double)SORB(j, t);

    __builtin_amdgcn_s_setprio(1);
    #pragma unroll 1
    for (int gi=0; gi<4; ++gi) {               // spin 1 -> SORB (same region)
      const int cb = (g4 + gi)*16 + lr;
      f64x4 ac = {0.0,0.0,0.0,0.0};
      #pragma unroll
      for (int kk=0;kk<16;kk++) {
        const int km = kk*4 + lq;
        ac = MFMA64((double)s_h[16+lr][km], (double)W_dn[(size_t)km*256 + cb], ac);
      }
      const int row = lq*4;
      #pragma unroll
      for (int v=0;v<4;v++)
        SORB(row+v, cb) = (float)(ac[v] + (double)b_dn[cb]);
    }
    __builtin_amdgcn_s_setprio(0);
    #pragma unroll
    for (int j=0;j<16;j++) a1r[j] = (double)SORB(j, t);

    // --- dual-spin LU: operand-identical to R9/R11's validated LU ---
    double prod0 = 1.0, prod1 = 1.0;
    int par0 = 0, par1 = 0;
    #pragma unroll
    for (int k=0;k<16;k++) {
      float bv0 = (r >= k) ? (float)fabs(a0r[k]) : -1.0f; int bi0 = r;
      float bv1 = (r >= k) ? (float)fabs(a1r[k]) : -1.0f; int bi1 = r;
      #pragma unroll
      for (int off=8; off>=1; off>>=1) {
        const float ov0 = __shfl_xor(bv0, off, 16); const int oi0 = __shfl_xor(bi0, off, 16);
        const float ov1 = __shfl_xor(bv1, off, 16); const int oi1 = __shfl_xor(bi1, off, 16);
        if (ov0 > bv0 || (ov0 == bv0 && oi0 < bi0)) { bv0 = ov0; bi0 = oi0; }
        if (ov1 > bv1 || (ov1 == bv1 && oi1 < bi1)) { bv1 = ov1; bi1 = oi1; }
      }
      const int p0 = bi0, p1 = bi1;
      par0 += (p0 != k) ? 1 : 0;
      par1 += (p1 != k) ? 1 : 0;
      const int src0 = (r == k) ? p0 : ((r == p0) ? k : r);
      const int src1 = (r == k) ? p1 : ((r == p1) ? k : r);
      const double piv0 = __shfl(a0r[k], p0, 16), nk0 = __shfl(a0r[k], src0, 16);
      const double piv1 = __shfl(a1r[k], p1, 16), nk1 = __shfl(a1r[k], src1, 16);
      prod0 *= piv0; prod1 *= piv1;
      const double f0 = (r > k && piv0 != 0.0) ? nk0/piv0 : 0.0;
      const double f1 = (r > k && piv1 != 0.0) ? nk1/piv1 : 0.0;
      a0r[k] = nk0; a1r[k] = nk1;
      #pragma unroll
      for (int j=k+1;j<16;j++) {
        const double sw0 = __shfl(a0r[j], src0, 16), kj0 = __shfl(a0r[j], p0, 16);
        const double sw1 = __shfl(a1r[j], src1, 16), kj1 = __shfl(a1r[j], p1, 16);
        a0r[j] = fma(-f0, kj0, sw0);
        a1r[j] = fma(-f1, kj1, sw1);
      }
    }
    if (r == 0) {
      s_lu[0][g] = log(fabs(prod0));
      s_su[0][g] = ((par0 + ((prod0 < 0.0) ? 1 : 0)) & 1) ? -1.f : 1.f;
      s_lu[1][g] = log(fabs(prod1));
      s_su[1][g] = ((par1 + ((prod1 < 0.0) ? 1 : 0)) & 1) ? -1.f : 1.f;
    }
  }
  __syncthreads();

  // ---- stage 7: signed logsumexp combine (f64, 16-thread parallel) ----
  if (t < 16) {
    const int k = t;
    const double wwk = (double)det_w[k];
    double mw = wwk;
    #pragma unroll
    for (int off=8; off>=1; off>>=1) mw = fmax(mw, __shfl_xor(mw, off, 16));
    const double ew = exp_d(wwk - mw);
    double sum = ew;
    #pragma unroll
    for (int off=8; off>=1; off>>=1) sum += __shfl_xor(sum, off, 16);
    const double lg = s_lu[0][k] + s_lu[1][k] + log(ew/sum + 1e-10);
    const double sg = (double)(s_su[0][k] * s_su[1][k]);
    double m2 = lg;
    #pragma unroll
    for (int off=8; off>=1; off>>=1) m2 = fmax(m2, __shfl_xor(m2, off, 16));
    double ssum = sg * exp_d(lg - m2);
    #pragma unroll
    for (int off=8; off>=1; off>>=1) ssum += __shfl_xor(ssum, off, 16);
    if (t == 0) {
      const double jas = (double)jscale[0] * (double)(s_red[0]+s_red[1]+s_red[2]+s_red[3]);
      out[w] = (float)(jas + m2 + log(fabs(ssum) + 1e-30));
      out[N_WALK + w] = (ssum > 0.0) ? 1.f : ((ssum < 0.0) ? -1.f : 0.f);
    }
  }
}

extern "C" void kernel_launch(void* const* d_in, const int* in_sizes, int n_in,
                              void* d_out, int out_size, void* d_ws, size_t ws_size,
                              hipStream_t stream) {
  const float* r_el  = (const float*)d_in[0];
  const float* cell  = (const float*)d_in[1];
  // d_in[2] = twist (unused by the reference)
  const float* W_e   = (const float*)d_in[3];
  const float* b_e   = (const float*)d_in[4];
  const float* W_pw  = (const float*)d_in[5];
  const float* b_pw  = (const float*)d_in[6];
  const float* W1    = (const float*)d_in[7];
  const float* b1    = (const float*)d_in[8];
  const float* W2    = (const float*)d_in[9];
  const float* b2    = (const float*)d_in[10];
  const float* ln_w  = (const float*)d_in[11];
  const float* ln_b  = (const float*)d_in[12];
  const float* W_up  = (const float*)d_in[13];
  const float* b_up  = (const float*)d_in[14];
  const float* W_dn  = (const float*)d_in[15];
  const float* b_dn  = (const float*)d_in[16];
  const float* det_w = (const float*)d_in[17];
  const float* Wj1   = (const float*)d_in[18];
  const float* bj1   = (const float*)d_in[19];
  const float* Wj2   = (const float*)d_in[20];
  const float* bj2   = (const float*)d_in[21];
  const float* Wj3   = (const float*)d_in[22];
  const float* bj3   = (const float*)d_in[23];
  const float* jsc   = (const float*)d_in[24];
  float* jtab = (float*)d_ws;    // (JTAB_N+1) floats = 32.8 KB scratch

  jtab_kernel<<<(JTAB_N + 1 + 255) / 256, 256, 0, stream>>>(
      Wj1, bj1, Wj2, bj2, Wj3, bj3, jtab);

  wf_kernel<<<N_WALK, 256, 0, stream>>>(
      r_el, cell, W_e, b_e, W_pw, b_pw, W1, b1, W2, b2, ln_w, ln_b,
      W_up, b_up, W_dn, b_dn, det_w, jtab, jsc,
      (float*)d_out);
}

// Round 13
// 440.670 us; speedup vs baseline: 1.3824x; 1.0978x over previous
//
#include <hip/hip_runtime.h>

#define N_WALK 4096
#define N_EL   32
#define DIM    64
#define HPAD   66   // f32 row stride: 66%32=2 -> 16 distinct banks for row-indexed reads
#define NLAY   3
#define KDET   16
#define NPAIR  496
#define TWO_PI_D 6.283185307179586476925286766559
#define JTAB_N    8192
#define JTAB_RMAX 5.25f

using f64x4 = __attribute__((ext_vector_type(4))) double;

#define MFMA64(A, B, C) __builtin_amdgcn_mfma_f64_16x16x4f64((A), (B), (C), 0, 0, 0)

// fast f64 exp, rel err ~3e-13 for |x| <= 60
__device__ __forceinline__ double exp_d(double x) {
  const double LOG2E  = 1.4426950408889634074;
  const double LN2_HI = 6.93147180369123816490e-01;
  const double LN2_LO = 1.90821492927058770002e-10;
  const double nf = rint(x * LOG2E);
  double r = fma(-nf, LN2_HI, x);
  r = fma(-nf, LN2_LO, r);
  double p = 1.0/3628800.0;
  p = fma(p, r, 1.0/362880.0);
  p = fma(p, r, 1.0/40320.0);
  p = fma(p, r, 1.0/5040.0);
  p = fma(p, r, 1.0/720.0);
  p = fma(p, r, 1.0/120.0);
  p = fma(p, r, 1.0/24.0);
  p = fma(p, r, 1.0/6.0);
  p = fma(p, r, 0.5);
  p = fma(p, r, 1.0);
  p = fma(p, r, 1.0);
  const long long bits = ((long long)((int)nf + 1023)) << 52;
  return p * __longlong_as_double(bits);
}

// silu with Newton-recip division (rel err ~1e-14)
__device__ __forceinline__ double silu_d(double x) {
  const double d = 1.0 + exp_d(-x);
  const double q0 = (double)(1.0f / (float)d);
  double q = q0 * (2.0 - d * q0);
  q = q * (2.0 - d * q);
  return x * q;
}
__device__ __forceinline__ float silu_q(float x) { return x / (1.0f + __expf(-x)); }

// ---- tiny pre-kernel: tabulate the scalar Jastrow MLP f(r) ----
__global__ __launch_bounds__(256) void jtab_kernel(
    const float* __restrict__ Wj1, const float* __restrict__ bj1,
    const float* __restrict__ Wj2, const float* __restrict__ bj2,
    const float* __restrict__ Wj3, const float* __restrict__ bj3,
    float* __restrict__ tab)
{
  const int i = blockIdx.x * 256 + threadIdx.x;
  if (i > JTAB_N) return;
  const float r = (float)i * (JTAB_RMAX / (float)JTAB_N);
  float h1[32];
  #pragma unroll
  for (int m=0;m<32;m++) h1[m] = silu_q(fmaf(r, Wj1[m], bj1[m]));
  float o = bj3[0];
  for (int n=0;n<32;n++) {
    float a2 = bj2[n];
    #pragma unroll
    for (int m=0;m<32;m++) a2 = fmaf(h1[m], Wj2[m*32+n], a2);
    o = fmaf(silu_q(a2), Wj3[n], o);
  }
  tab[i] = o;
}

__global__ __launch_bounds__(256) void wf_kernel(
    const float* __restrict__ r_el,
    const float* __restrict__ cell,
    const float* __restrict__ W_e,  const float* __restrict__ b_e,
    const float* __restrict__ W_pw, const float* __restrict__ b_pw,
    const float* __restrict__ W1,   const float* __restrict__ b1,
    const float* __restrict__ W2,   const float* __restrict__ b2,
    const float* __restrict__ ln_w, const float* __restrict__ ln_b,
    const float* __restrict__ W_up, const float* __restrict__ b_up,
    const float* __restrict__ W_dn, const float* __restrict__ b_dn,
    const float* __restrict__ det_w,
    const float* __restrict__ jtab,
    const float* __restrict__ jscale,
    float* __restrict__ out)
{
  __shared__ float s_linv[9];
  __shared__ float s_cl[9];
  __shared__ float s_r[N_EL][3];
  __shared__ float s_h[N_EL][HPAD];
  // union buffer: SY [32][66]=2112 | s_pw at [2112,2304) | SORB [16][257]=4112
  __shared__ float s_u[16*257];
  __shared__ float s_hm[DIM];
  __shared__ double s_hb[DIM];        // b1 + hm @ W1[64:128]  (f64, per layer)
  __shared__ double s_lu[2][KDET];
  __shared__ float  s_su[2][KDET];
  __shared__ float  s_red[4];
#define SY(e,d)   s_u[(e)*HPAD + (d)]
#define SPW(e,i)  s_u[2112 + (e)*6 + (i)]
#define SORB(j,c) s_u[(j)*257 + (c)]

  const int t = threadIdx.x;
  const int w = blockIdx.x;
  const int wv = t >> 6;         // wave id 0..3
  const int l  = t & 63;
  const int lr = l & 15;         // row/col fragment index
  const int lq = l >> 4;         // k fragment index

  // ---- cell inverse: f64 compute, f32 round ----
  if (t == 0) {
    double m00=cell[0], m01=cell[1], m02=cell[2];
    double m10=cell[3], m11=cell[4], m12=cell[5];
    double m20=cell[6], m21=cell[7], m22=cell[8];
    double c00 = m11*m22 - m12*m21;
    double c10 = m12*m20 - m10*m22;
    double c20 = m10*m21 - m11*m20;
    double det = m00*c00 + m01*c10 + m02*c20;
    double id = 1.0/det;
    s_linv[0]=(float)(c00*id); s_linv[1]=(float)((m02*m21-m01*m22)*id); s_linv[2]=(float)((m01*m12-m02*m11)*id);
    s_linv[3]=(float)(c10*id); s_linv[4]=(float)((m00*m22-m02*m20)*id); s_linv[5]=(float)((m02*m10-m00*m12)*id);
    s_linv[6]=(float)(c20*id); s_linv[7]=(float)((m01*m20-m00*m21)*id); s_linv[8]=(float)((m00*m11-m01*m10)*id);
    #pragma unroll
    for (int i=0;i<9;i++) s_cl[i]=cell[i];
  }
  __syncthreads();

  // ---- stage 1 (merged): wrap + plane waves in ONE phase.
  //      Lane (e, ax): redundantly computes the wrap for electron e
  //      (bitwise-identical f32 sequence to R12), then its own axis sincos.
  //      ax==3 lane stores s_r. One barrier instead of two. ----
  if (t < 128) {
    const int e = t >> 2, ax = t & 3;
    const float* rp = r_el + ((size_t)w * N_EL + e) * 3;
    const float rx = rp[0], ry = rp[1], rz = rp[2];
    float s0 = (float)((double)s_linv[0]*rx + (double)s_linv[1]*ry + (double)s_linv[2]*rz);
    float s1 = (float)((double)s_linv[3]*rx + (double)s_linv[4]*ry + (double)s_linv[5]*rz);
    float s2 = (float)((double)s_linv[6]*rx + (double)s_linv[7]*ry + (double)s_linv[8]*rz);
    s0 -= floorf(s0); s1 -= floorf(s1); s2 -= floorf(s2);
    const float wx = (float)((double)s0*s_cl[0] + (double)s1*s_cl[3] + (double)s2*s_cl[6]);
    const float wy = (float)((double)s0*s_cl[1] + (double)s1*s_cl[4] + (double)s2*s_cl[7]);
    const float wz = (float)((double)s0*s_cl[2] + (double)s1*s_cl[5] + (double)s2*s_cl[8]);
    if (ax == 3) {
      s_r[e][0]=wx; s_r[e][1]=wy; s_r[e][2]=wz;
    } else {
      const float u = (float)((double)s_linv[3*ax+0]*wx + (double)s_linv[3*ax+1]*wy + (double)s_linv[3*ax+2]*wz);
      double sn, cs;
      sincos(TWO_PI_D*(double)u, &sn, &cs);
      SPW(e, ax)   = (float)sn;
      SPW(e, ax+3) = (float)cs;
    }
  }
  __syncthreads();

  // ---- stage 2: h0 (f64 acc -> f32 store) ----
  {
    const int e = t >> 3, db = (t & 7) * 8;
    const double rx=s_r[e][0], ry=s_r[e][1], rz=s_r[e][2];
    const double p0=SPW(e,0),p1=SPW(e,1),p2=SPW(e,2);
    const double p3=SPW(e,3),p4=SPW(e,4),p5=SPW(e,5);
    #pragma unroll
    for (int u=0;u<8;u++) {
      const int d = db+u;
      double acc = (double)b_e[d] + (double)b_pw[d];
      acc = fma(rx, (double)W_e[0*DIM+d], acc);
      acc = fma(ry, (double)W_e[1*DIM+d], acc);
      acc = fma(rz, (double)W_e[2*DIM+d], acc);
      acc = fma(p0, (double)W_pw[0*DIM+d], acc);
      acc = fma(p1, (double)W_pw[1*DIM+d], acc);
      acc = fma(p2, (double)W_pw[2*DIM+d], acc);
      acc = fma(p3, (double)W_pw[3*DIM+d], acc);
      acc = fma(p4, (double)W_pw[4*DIM+d], acc);
      acc = fma(p5, (double)W_pw[5*DIM+d], acc);
      s_h[e][d] = (float)acc;
    }
  }
  __syncthreads();

  const int m  = wv & 1;
  const int nb = (wv >> 1) * 2;
  const int ea = m*16 + lr;        // A-fragment row (electron)
  const int c0 = nb*16 + lr;       // D/B column of tile 0 (tile 1 = c0+16)
  const int er = m*16 + lq*4;      // D row base

  // ---- stage 3: interaction layers via f64 MFMA ----
  for (int L = 0; L < NLAY; ++L) {
    const float* __restrict__ w1p = W1 + (size_t)L*192*DIM;
    const float* __restrict__ w2p = W2 + (size_t)L*DIM*DIM;

    // Per-wave prologue, NO barrier (R12-validated):
    //  hm redundant per wave (bit-identical, benign race); hb own 32 cols,
    //  2 lanes/col halves combined via shfl.
    {
      double s = 0.0;
      #pragma unroll 8
      for (int e=0;e<N_EL;e++) s += (double)s_h[e][l];
      s_hm[l] = (float)(s * (1.0/N_EL));
      const int c = nb*16 + (l & 31);
      const int half = l >> 5;
      double hb = (half == 0) ? (double)b1[L*DIM + c] : 0.0;
      const int k0 = half*32;
      #pragma unroll 8
      for (int km=k0; km<k0+32; km++)
        hb = fma((double)s_hm[km], (double)w1p[(64+km)*DIM + c], hb);
      hb += __shfl_xor(hb, 32, 64);
      if (half == 0) s_hb[c] = hb;
    }

    // --- y = silu(h@W1a + (h*hm)@W1c + hb) ---
    {
      f64x4 a0 = {0.0,0.0,0.0,0.0}, a1 = {0.0,0.0,0.0,0.0};
      #pragma unroll
      for (int kk=0;kk<16;kk++) {              // K seg 0: x = h
        const int km = kk*4 + lq;
        const double af = (double)s_h[ea][km];
        const double q0 = (double)w1p[km*DIM + c0];
        const double q1 = (double)w1p[km*DIM + c0 + 16];
        a0 = MFMA64(af, q0, a0);
        a1 = MFMA64(af, q1, a1);
      }
      #pragma unroll
      for (int kk=0;kk<16;kk++) {              // K seg 2: x = h*hm (f32 product)
        const int km = kk*4 + lq;
        const double af = (double)(s_h[ea][km] * s_hm[km]);
        const double q0 = (double)w1p[(128+km)*DIM + c0];
        const double q1 = (double)w1p[(128+km)*DIM + c0 + 16];
        a0 = MFMA64(af, q0, a0);
        a1 = MFMA64(af, q1, a1);
      }
      #pragma unroll
      for (int v=0;v<4;v++) {
        const float p0 = (float)(a0[v] + s_hb[c0]);        // np pre-act (f64 reorder)
        const float p1 = (float)(a1[v] + s_hb[c0 + 16]);
        SY(er+v, c0)      = (float)silu_d((double)p0);
        SY(er+v, c0 + 16) = (float)silu_d((double)p1);
      }
    }
    __syncthreads();

    // --- delta = y @ W2 + b2 ; v = h + delta written DIRECTLY to s_h ---
    {
      f64x4 a0 = {0.0,0.0,0.0,0.0}, a1 = {0.0,0.0,0.0,0.0};
      #pragma unroll
      for (int kk=0;kk<16;kk++) {
        const int km = kk*4 + lq;
        const double af = (double)SY(ea, km);
        const double q0 = (double)w2p[km*DIM + c0];
        const double q1 = (double)w2p[km*DIM + c0 + 16];
        a0 = MFMA64(af, q0, a0);
        a1 = MFMA64(af, q1, a1);
      }
      #pragma unroll
      for (int v=0;v<4;v++) {
        const float d0 = (float)(a0[v] + (double)b2[L*DIM + c0]);      // np delta
        const float d1 = (float)(a1[v] + (double)b2[L*DIM + c0 + 16]);
        s_h[er+v][c0]      = s_h[er+v][c0]      + d0;                  // np h+delta
        s_h[er+v][c0 + 16] = s_h[er+v][c0 + 16] + d1;
      }
    }
    __syncthreads();

    // --- LayerNorm: stats f64 (Newton rstd), reads v from s_h, writes s_h ---
    {
      const int e = t >> 3, db = (t & 7) * 8;
      float v[8];
      double ps=0.0, pss=0.0;
      #pragma unroll
      for (int u=0;u<8;u++) {
        v[u] = s_h[e][db+u];
        ps += (double)v[u]; pss += (double)v[u]*(double)v[u];
      }
      #pragma unroll
      for (int off=4; off>=1; off>>=1) {
        ps  += __shfl_xor(ps,  off, 8);
        pss += __shfl_xor(pss, off, 8);
      }
      const double mu = ps * (1.0/DIM);
      double var = pss * (1.0/DIM) - mu*mu;
      var = fmax(var, 0.0);
      const double s = var + 1e-5;
      double rstd = (double)rsqrtf((float)s);
      rstd = rstd * (1.5 - 0.5*s*rstd*rstd);
      rstd = rstd * (1.5 - 0.5*s*rstd*rstd);
      #pragma unroll
      for (int u=0;u<8;u++) {
        const int d = db+u;
        s_h[e][d] = (float)(((double)v[u]-mu)*rstd*(double)ln_w[L*DIM+d] + (double)ln_b[L*DIM+d]);
      }
    }
    __syncthreads();
  }

  // ---- stage 4: Jastrow via table lookup ----
  float jpart = 0.f;
  for (int p = t; p < NPAIR; p += 256) {
    int i = 0, rem = p;
    while (rem >= (N_EL-1) - i) { rem -= (N_EL-1) - i; ++i; }
    const int j = i + 1 + rem;
    const float dx = s_r[i][0]-s_r[j][0];
    const float dy = s_r[i][1]-s_r[j][1];
    const float dz = s_r[i][2]-s_r[j][2];
    float q0 = (float)((double)s_linv[0]*dx + (double)s_linv[1]*dy + (double)s_linv[2]*dz);
    float q1 = (float)((double)s_linv[3]*dx + (double)s_linv[4]*dy + (double)s_linv[5]*dz);
    float q2 = (float)((double)s_linv[6]*dx + (double)s_linv[7]*dy + (double)s_linv[8]*dz);
    q0 -= rintf(q0); q1 -= rintf(q1); q2 -= rintf(q2);
    const float vx = (float)((double)q0*s_cl[0] + (double)q1*s_cl[3] + (double)q2*s_cl[6]);
    const float vy = (float)((double)q0*s_cl[1] + (double)q1*s_cl[4] + (double)q2*s_cl[7]);
    const float vz = (float)((double)q0*s_cl[2] + (double)q1*s_cl[5] + (double)q2*s_cl[8]);
    const float rij = sqrtf(vx*vx + vy*vy + vz*vz);
    const float u = rij * ((float)JTAB_N / JTAB_RMAX);
    int i0 = (int)u;
    i0 = (i0 > JTAB_N-1) ? (JTAB_N-1) : i0;
    const float fr = u - (float)i0;
    const float f0 = jtab[i0], f1 = jtab[i0+1];
    jpart += fmaf(fr, f1 - f0, f0);
  }
  #pragma unroll
  for (int off=32; off>=1; off>>=1) jpart += __shfl_xor(jpart, off, 64);
  if ((t & 63) == 0) s_red[t >> 6] = jpart;

  // ---- stage 5+6: both spins' orbitals via f64 MFMA (LDS-staged f32 round),
  //      then dual-spin VIRTUAL-PIVOT LU. No barriers (wave-private slab).
  {
    const int g4 = wv * 4;
    const int g  = t >> 4;
    const int r  = t & 15;
    double a0r[16], a1r[16];

    __builtin_amdgcn_s_setprio(1);
    #pragma unroll 1
    for (int gi=0; gi<4; ++gi) {               // spin 0 -> SORB
      const int cb = (g4 + gi)*16 + lr;
      f64x4 ac = {0.0,0.0,0.0,0.0};
      #pragma unroll
      for (int kk=0;kk<16;kk++) {
        const int km = kk*4 + lq;
        ac = MFMA64((double)s_h[lr][km], (double)W_up[(size_t)km*256 + cb], ac);
      }
      const int row = lq*4;
      #pragma unroll
      for (int v=0;v<4;v++)
        SORB(row+v, cb) = (float)(ac[v] + (double)b_up[cb]);
    }
    __builtin_amdgcn_s_setprio(0);
    #pragma unroll
    for (int j=0;j<16;j++) a0r[j] = (double)SORB(j, t);

    __builtin_amdgcn_s_setprio(1);
    #pragma unroll 1
    for (int gi=0; gi<4; ++gi) {               // spin 1 -> SORB (same region)
      const int cb = (g4 + gi)*16 + lr;
      f64x4 ac = {0.0,0.0,0.0,0.0};
      #pragma unroll
      for (int kk=0;kk<16;kk++) {
        const int km = kk*4 + lq;
        ac = MFMA64((double)s_h[16+lr][km], (double)W_dn[(size_t)km*256 + cb], ac);
      }
      const int row = lq*4;
      #pragma unroll
      for (int v=0;v<4;v++)
        SORB(row+v, cb) = (float)(ac[v] + (double)b_dn[cb]);
    }
    __builtin_amdgcn_s_setprio(0);
    #pragma unroll
    for (int j=0;j<16;j++) a1r[j] = (double)SORB(j, t);

    // --- dual-spin LU, VIRTUAL partial pivoting: rows never move; per step
    //     argmax over not-done lanes (done lanes bid -1), pivot row broadcast
    //     with 1 shfl per column; parity = inversion count of the step map.
    //     Same pivot values / fma operands as the physical-swap LU. ---
    double prod0 = 1.0, prod1 = 1.0;
    int done0 = 0, done1 = 0, step0 = 0, step1 = 0;
    #pragma unroll
    for (int k=0;k<16;k++) {
      float bv0 = done0 ? -1.0f : (float)fabs(a0r[k]); int bi0 = r;
      float bv1 = done1 ? -1.0f : (float)fabs(a1r[k]); int bi1 = r;
      #pragma unroll
      for (int off=8; off>=1; off>>=1) {
        const float ov0 = __shfl_xor(bv0, off, 16); const int oi0 = __shfl_xor(bi0, off, 16);
        const float ov1 = __shfl_xor(bv1, off, 16); const int oi1 = __shfl_xor(bi1, off, 16);
        if (ov0 > bv0 || (ov0 == bv0 && oi0 < bi0)) { bv0 = ov0; bi0 = oi0; }
        if (ov1 > bv1 || (ov1 == bv1 && oi1 < bi1)) { bv1 = ov1; bi1 = oi1; }
      }
      const int p0 = bi0, p1 = bi1;
      const double piv0 = __shfl(a0r[k], p0, 16);
      const double piv1 = __shfl(a1r[k], p1, 16);
      prod0 *= piv0; prod1 *= piv1;
      if (r == p0) { done0 = 1; step0 = k; }
      if (r == p1) { done1 = 1; step1 = k; }
      const double f0 = (!done0 && piv0 != 0.0) ? a0r[k]/piv0 : 0.0;
      const double f1 = (!done1 && piv1 != 0.0) ? a1r[k]/piv1 : 0.0;
      #pragma unroll
      for (int j=k+1;j<16;j++) {
        const double kj0 = __shfl(a0r[j], p0, 16);
        const double kj1 = __shfl(a1r[j], p1, 16);
        a0r[j] = fma(-f0, kj0, a0r[j]);
        a1r[j] = fma(-f1, kj1, a1r[j]);
      }
    }
    // parity: inversion count of the row->step map, summed over lanes
    int inv0 = 0, inv1 = 0;
    #pragma unroll
    for (int s2=0;s2<16;s2++) {
      const int os0 = __shfl(step0, s2, 16);
      const int os1 = __shfl(step1, s2, 16);
      inv0 += (s2 < r && os0 > step0) ? 1 : 0;
      inv1 += (s2 < r && os1 > step1) ? 1 : 0;
    }
    #pragma unroll
    for (int off=8; off>=1; off>>=1) {
      inv0 += __shfl_xor(inv0, off, 16);
      inv1 += __shfl_xor(inv1, off, 16);
    }
    if (r == 0) {
      s_lu[0][g] = log(fabs(prod0));
      s_su[0][g] = ((inv0 + ((prod0 < 0.0) ? 1 : 0)) & 1) ? -1.f : 1.f;
      s_lu[1][g] = log(fabs(prod1));
      s_su[1][g] = ((inv1 + ((prod1 < 0.0) ? 1 : 0)) & 1) ? -1.f : 1.f;
    }
  }
  __syncthreads();

  // ---- stage 7: signed logsumexp combine (f64, 16-thread parallel) ----
  if (t < 16) {
    const int k = t;
    const double wwk = (double)det_w[k];
    double mw = wwk;
    #pragma unroll
    for (int off=8; off>=1; off>>=1) mw = fmax(mw, __shfl_xor(mw, off, 16));
    const double ew = exp_d(wwk - mw);
    double sum = ew;
    #pragma unroll
    for (int off=8; off>=1; off>>=1) sum += __shfl_xor(sum, off, 16);
    const double lg = s_lu[0][k] + s_lu[1][k] + log(ew/sum + 1e-10);
    const double sg = (double)(s_su[0][k] * s_su[1][k]);
    double m2 = lg;
    #pragma unroll
    for (int off=8; off>=1; off>>=1) m2 = fmax(m2, __shfl_xor(m2, off, 16));
    double ssum = sg * exp_d(lg - m2);
    #pragma unroll
    for (int off=8; off>=1; off>>=1) ssum += __shfl_xor(ssum, off, 16);
    if (t == 0) {
      const double jas = (double)jscale[0] * (double)(s_red[0]+s_red[1]+s_red[2]+s_red[3]);
      out[w] = (float)(jas + m2 + log(fabs(ssum) + 1e-30));
      out[N_WALK + w] = (ssum > 0.0) ? 1.f : ((ssum < 0.0) ? -1.f : 0.f);
    }
  }
}

extern "C" void kernel_launch(void* const* d_in, const int* in_sizes, int n_in,
                              void* d_out, int out_size, void* d_ws, size_t ws_size,
                              hipStream_t stream) {
  const float* r_el  = (const float*)d_in[0];
  const float* cell  = (const float*)d_in[1];
  // d_in[2] = twist (unused by the reference)
  const float* W_e   = (const float*)d_in[3];
  const float* b_e   = (const float*)d_in[4];
  const float* W_pw  = (const float*)d_in[5];
  const float* b_pw  = (const float*)d_in[6];
  const float* W1    = (const float*)d_in[7];
  const float* b1    = (const float*)d_in[8];
  const float* W2    = (const float*)d_in[9];
  const float* b2    = (const float*)d_in[10];
  const float* ln_w  = (const float*)d_in[11];
  const float* ln_b  = (const float*)d_in[12];
  const float* W_up  = (const float*)d_in[13];
  const float* b_up  = (const float*)d_in[14];
  const float* W_dn  = (const float*)d_in[15];
  const float* b_dn  = (const float*)d_in[16];
  const float* det_w = (const float*)d_in[17];
  const float* Wj1   = (const float*)d_in[18];
  const float* bj1   = (const float*)d_in[19];
  const float* Wj2   = (const float*)d_in[20];
  const float* bj2   = (const float*)d_in[21];
  const float* Wj3   = (const float*)d_in[22];
  const float* bj3   = (const float*)d_in[23];
  const float* jsc   = (const float*)d_in[24];
  float* jtab = (float*)d_ws;    // (JTAB_N+1) floats = 32.8 KB scratch

  jtab_kernel<<<(JTAB_N + 1 + 255) / 256, 256, 0, stream>>>(
      Wj1, bj1, Wj2, bj2, Wj3, bj3, jtab);

  wf_kernel<<<N_WALK, 256, 0, stream>>>(
      r_el, cell, W_e, b_e, W_pw, b_pw, W1, b1, W2, b2, ln_w, ln_b,
      W_up, b_up, W_dn, b_dn, det_w, jtab, jsc,
      (float*)d_out);
}